// Round 1
// baseline (5623.255 us; speedup 1.0000x reference)
//
#include <hip/hip_runtime.h>

#define SS 1024
#define BB 2048
#define NB 8
#define NT 256

typedef unsigned int u32;
typedef unsigned short u16;

// ---------- shared memory layout (65232 B <= 64 KiB) ----------
struct SMem {
  u32 Wf1[128][36];   // [row][dword]: d<16 -> Wih_f1 cols (2d,2d+1); d>=16 -> Whh_f1 cols (2(d-16), +1)
  u32 Wb1[128][36];   // same for backward layer-1
  u32 W0f[128][20];   // Whh_f0, 16 dwords used (32 cols), stride 20 dw = 80 B (16B aligned, conflict-free)
  u32 W0b[128][20];
  float bias[4][128]; // 0:f0 1:f1 2:b0 3:b1
  float wxf[128];     // Wih_f0 column
  float wxb[128];
  float wlin[68];     // [0..63] Wlin, [64] blin
  float hf0[NB][36];
  float hb0[NB][36];
  float hf1[NB][36];
  float hb1[NB][34];  // [b][32]=x_t broadcast, [b][33]=xb_t broadcast
};

// ---------- helpers ----------
__device__ __forceinline__ float bits2f(u32 u) { return __uint_as_float(u); }
__device__ __forceinline__ u16 f2bf(float f) {  // RNE fp32->bf16
  u32 u = __float_as_uint(f);
  u32 r = (u + 0x7fffu + ((u >> 16) & 1u)) >> 16;
  return (u16)r;
}
__device__ __forceinline__ float ldin(const void* p, int i, bool bf) {
  if (bf) { u16 v = ((const u16*)p)[i]; return __uint_as_float(((u32)v) << 16); }
  return ((const float*)p)[i];
}
__device__ __forceinline__ u16 ldbf(const void* p, int i, bool bf) {
  if (bf) return ((const u16*)p)[i];
  return f2bf(((const float*)p)[i]);
}
__device__ __forceinline__ float sigf(float x) {
  // 1/(1+e^-x); inf-safe at both ends
  return __builtin_amdgcn_rcpf(1.0f + __expf(-x));
}
__device__ __forceinline__ float tanh_f(float x) {
  // 1 - 2/(e^{2x}+1); inf-safe (no inf/inf)
  return 1.0f - 2.0f * __builtin_amdgcn_rcpf(__expf(2.0f * x) + 1.0f);
}
__device__ __forceinline__ float combine(const float acc[4], float& c) {
  float ig = sigf(acc[0]);
  float fg = sigf(acc[1]);
  float gg = tanh_f(acc[2]);
  float og = sigf(acc[3]);
  c = fg * c + ig * gg;
  return og * tanh_f(c);
}

// gate dot: rows {j, 32+j, 64+j, 96+j} of W (packed bf16x2), input vec in registers
template<int KD, int STRIDE>
__device__ __forceinline__ void gdot(const u32* W, int j, const float* inr, float acc[4]) {
#pragma unroll
  for (int g = 0; g < 4; ++g) {
    const uint4* row4 = (const uint4*)(W + (g * 32 + j) * STRIDE);
    float a0 = 0.f, a1 = 0.f;
#pragma unroll
    for (int d4 = 0; d4 < KD / 4; ++d4) {
      uint4 w = row4[d4];
      a0 = fmaf(bits2f(w.x << 16), inr[8 * d4 + 0], a0);
      a1 = fmaf(bits2f(w.x & 0xffff0000u), inr[8 * d4 + 1], a1);
      a0 = fmaf(bits2f(w.y << 16), inr[8 * d4 + 2], a0);
      a1 = fmaf(bits2f(w.y & 0xffff0000u), inr[8 * d4 + 3], a1);
      a0 = fmaf(bits2f(w.z << 16), inr[8 * d4 + 4], a0);
      a1 = fmaf(bits2f(w.z & 0xffff0000u), inr[8 * d4 + 5], a1);
      a0 = fmaf(bits2f(w.w << 16), inr[8 * d4 + 6], a0);
      a1 = fmaf(bits2f(w.w & 0xffff0000u), inr[8 * d4 + 7], a1);
    }
    acc[g] += a0 + a1;
  }
}

__device__ __forceinline__ void ld32(const float* src, float* inr) {
#pragma unroll
  for (int i = 0; i < 8; ++i) {
    float4 v = ((const float4*)src)[i];
    inr[4 * i + 0] = v.x; inr[4 * i + 1] = v.y; inr[4 * i + 2] = v.z; inr[4 * i + 3] = v.w;
  }
}

__global__ __launch_bounds__(NT, 1) void lstm_kernel(
    const void* __restrict__ xg,
    const void* Wih_f0, const void* Whh_f0, const void* b_f0,
    const void* Wih_f1, const void* Whh_f1, const void* b_f1,
    const void* Wih_b0, const void* Whh_b0, const void* b_b0,
    const void* Wih_b1, const void* Whh_b1, const void* b_b1,
    const void* Wlin, const void* blin, const int* __restrict__ futp,
    void* __restrict__ outp) {
  __shared__ SMem sm;
  const int tid = threadIdx.x;
  const int bid = blockIdx.x;
  const int j = tid >> 3, b = tid & 7;

  // ---- dtype detection: are float tensors fp32 or bf16? (uniform across all threads/blocks)
  bool bfm;
  {
    const float* xf = (const float*)xg;
    int bad = 0;
    for (int i = 0; i < 64; ++i) {
      float v = xf[i];
      float a = fabsf(v);
      bool ok = (a == 0.0f) || (a > 1e-8f && a < 1e4f);  // NaN -> false
      if (!ok) bad = 1;
    }
    bfm = (bad != 0);  // fp32 data always plausible; bf16-pairs-as-fp32 essentially never
  }

  // ---- stage weights into LDS (packed bf16x2) ----
  for (int idx = tid; idx < 128 * 32; idx += NT) {
    int r = idx >> 5, d = idx & 31;
    int src = (d < 16) ? (r * 32 + 2 * d) : (r * 32 + 2 * (d - 16));
    const void* pf1 = (d < 16) ? Wih_f1 : Whh_f1;
    const void* pb1 = (d < 16) ? Wih_b1 : Whh_b1;
    sm.Wf1[r][d] = (u32)ldbf(pf1, src, bfm) | ((u32)ldbf(pf1, src + 1, bfm) << 16);
    sm.Wb1[r][d] = (u32)ldbf(pb1, src, bfm) | ((u32)ldbf(pb1, src + 1, bfm) << 16);
  }
  for (int idx = tid; idx < 128 * 16; idx += NT) {
    int r = idx >> 4, d = idx & 15;
    int src = r * 32 + 2 * d;
    sm.W0f[r][d] = (u32)ldbf(Whh_f0, src, bfm) | ((u32)ldbf(Whh_f0, src + 1, bfm) << 16);
    sm.W0b[r][d] = (u32)ldbf(Whh_b0, src, bfm) | ((u32)ldbf(Whh_b0, src + 1, bfm) << 16);
  }
  if (tid < 128) {
    sm.wxf[tid] = ldin(Wih_f0, tid, bfm);
    sm.wxb[tid] = ldin(Wih_b0, tid, bfm);
    sm.bias[0][tid] = ldin(b_f0, tid, bfm);
    sm.bias[1][tid] = ldin(b_f1, tid, bfm);
    sm.bias[2][tid] = ldin(b_b0, tid, bfm);
    sm.bias[3][tid] = ldin(b_b1, tid, bfm);
  } else if (tid < 192) {
    int k = tid - 128;
    sm.wlin[k] = ldin(Wlin, k, bfm);
  } else if (tid == 192) {
    sm.wlin[64] = ldin(blin, 0, bfm);
  }
  // zero h state (hf0,hb0,hf1 contiguous in struct)
  for (int idx = tid; idx < 3 * NB * 36; idx += NT) (&sm.hf0[0][0])[idx] = 0.f;
  for (int idx = tid; idx < NB * 34; idx += NT) (&sm.hb1[0][0])[idx] = 0.f;
  __syncthreads();

  const int fut = *futp;
  if (tid < NB) {
    sm.hb1[tid][32] = ldin(xg, 0 * BB + bid * NB + tid, bfm);  // x_0
  } else if (tid < 2 * NB) {
    int bb2 = tid - NB;
    int ib = ((fut % SS) + SS) % SS;                           // xb_0 index
    sm.hb1[bb2][33] = ldin(xg, ib * BB + bid * NB + bb2, bfm);
  }
  __syncthreads();

  // ---- time loop: c-state in registers, h-state in LDS ----
  float c_f0 = 0.f, c_f1 = 0.f, c_b0 = 0.f, c_b1 = 0.f;
  float xv = 0.f, xbv = 0.f;

  for (int t = 0; t < SS; ++t) {
    // prefetch x_{t+1} into registers (published at end of step)
    if (t + 1 < SS) {
      if (tid < NB) {
        xv = ldin(xg, (t + 1) * BB + bid * NB + tid, bfm);
      } else if (tid < 2 * NB) {
        int ib = (((fut - (t + 1)) % SS) + SS) % SS;
        xbv = ldin(xg, ib * BB + bid * NB + (tid - NB), bfm);
      }
    }

    // --- f0 & b0 (independent; read h_{t-1}) ---
    float hnf0, hnb0;
    {
      float inr[32];
      ld32(sm.hf0[b], inr);
      float xcur = sm.hb1[b][32];
      float acc[4];
#pragma unroll
      for (int g = 0; g < 4; ++g) acc[g] = sm.bias[0][g * 32 + j] + sm.wxf[g * 32 + j] * xcur;
      gdot<16, 20>(&sm.W0f[0][0], j, inr, acc);
      hnf0 = combine(acc, c_f0);
    }
    {
      float inr[32];
      ld32(sm.hb0[b], inr);
      float xcur = sm.hb1[b][33];
      float acc[4];
#pragma unroll
      for (int g = 0; g < 4; ++g) acc[g] = sm.bias[2][g * 32 + j] + sm.wxb[g * 32 + j] * xcur;
      gdot<16, 20>(&sm.W0b[0][0], j, inr, acc);
      hnb0 = combine(acc, c_b0);
    }
    __syncthreads();  // A: all reads of old hf0/hb0 complete
    sm.hf0[b][j] = hnf0;
    sm.hb0[b][j] = hnb0;
    __syncthreads();  // 1: new hf0/hb0 visible

    // --- f1: inp = new hf0, h = old hf1 ---
    float hnf1;
    {
      float inr[64];
      ld32(sm.hf0[b], inr);
      ld32(sm.hf1[b], inr + 32);
      float acc[4];
#pragma unroll
      for (int g = 0; g < 4; ++g) acc[g] = sm.bias[1][g * 32 + j];
      gdot<32, 36>(&sm.Wf1[0][0], j, inr, acc);
      hnf1 = combine(acc, c_f1);
    }
    __syncthreads();  // B: reads of old hf1 complete
    sm.hf1[b][j] = hnf1;
    __syncthreads();  // 2: new hf1 visible

    // --- b1 (reference bug replicated): inp = new hb0, h = NEW hf1, c = cb1 ---
    {
      float inr[64];
      ld32(sm.hb0[b], inr);
      ld32(sm.hf1[b], inr + 32);
      float acc[4];
#pragma unroll
      for (int g = 0; g < 4; ++g) acc[g] = sm.bias[3][g * 32 + j];
      gdot<32, 36>(&sm.Wb1[0][0], j, inr, acc);
      float hnb1 = combine(acc, c_b1);
      sm.hb1[b][j] = hnb1;  // only output phase reads hb1
    }
    __syncthreads();  // 3: hb1 visible

    // --- output head + publish next x ---
    if (tid < NB) {
      float o = sm.wlin[64];
#pragma unroll
      for (int k = 0; k < 32; ++k) o = fmaf(sm.wlin[k], sm.hf1[tid][k], o);
#pragma unroll
      for (int k = 0; k < 32; ++k) o = fmaf(sm.wlin[32 + k], sm.hb1[tid][k], o);
      size_t pos = (size_t)(bid * NB + tid) * SS + (size_t)t;
      if (bfm) ((u16*)outp)[pos] = f2bf(o);
      else     ((float*)outp)[pos] = o;
      sm.hb1[tid][32] = xv;
    } else if (tid < 2 * NB) {
      sm.hb1[tid - NB][33] = xbv;
    }
    __syncthreads();  // 4: step complete
  }
}

extern "C" void kernel_launch(void* const* d_in, const int* in_sizes, int n_in,
                              void* d_out, int out_size, void* d_ws, size_t ws_size,
                              hipStream_t stream) {
  (void)in_sizes; (void)n_in; (void)out_size; (void)d_ws; (void)ws_size;
  lstm_kernel<<<dim3(BB / NB), dim3(NT), 0, stream>>>(
      d_in[0], d_in[1], d_in[2], d_in[3], d_in[4], d_in[5], d_in[6],
      d_in[7], d_in[8], d_in[9], d_in[10], d_in[11], d_in[12],
      d_in[13], d_in[14], (const int*)d_in[15], d_out);
}

// Round 2
// 2390.183 us; speedup vs baseline: 2.3526x; 2.3526x over previous
//
#include <hip/hip_runtime.h>

#define SS 1024
#define BB 2048
#define NT 256

typedef unsigned int u32;
typedef unsigned short u16;
typedef _Float16 half2v __attribute__((ext_vector_type(2)));

#define WS1 36   // row stride (dwords) for K=64 cells (32 dw used) — 16B aligned
#define WS0 20   // row stride for K=32 cells (16 dw used)

// ---------- shared memory: weights packed f16x2 + per-wave h buffers (~59 KB) ----------
struct SMem {
  u32 Wf1[128 * WS1];     // [Wih_f1 | Whh_f1] rows, f16 pairs along K
  u32 Wb1[128 * WS1];
  u32 W0f[128 * WS0];     // Whh_f0
  u32 W0b[128 * WS0];     // Whh_b0
  u32 h[3][4][2][20];     // [cell: 0=hf0 1=hb0 2=hf1][wave][b2][20 dw], f16x2, 16 used
};

#define LDS_FENCE() asm volatile("s_waitcnt lgkmcnt(0)" ::: "memory")

// ---------- helpers ----------
__device__ __forceinline__ u16 f2bf(float f) {  // RNE fp32->bf16
  u32 u = __float_as_uint(f);
  return (u16)((u + 0x7fffu + ((u >> 16) & 1u)) >> 16);
}
__device__ __forceinline__ float ldin(const void* p, int i, bool bf) {
  if (bf) { u16 v = ((const u16*)p)[i]; return __uint_as_float(((u32)v) << 16); }
  return ((const float*)p)[i];
}
__device__ __forceinline__ u32 pack2h(float a, float b) {  // two f32 -> packed f16x2 (RNE)
  _Float16 ha = (_Float16)a, hb = (_Float16)b;
  u16 ua = __builtin_bit_cast(u16, ha), ub = __builtin_bit_cast(u16, hb);
  return (u32)ua | ((u32)ub << 16);
}
__device__ __forceinline__ float sigf(float x) {
  return __builtin_amdgcn_rcpf(1.0f + __expf(-x));
}
__device__ __forceinline__ float tanh_f(float x) {
  return 1.0f - 2.0f * __builtin_amdgcn_rcpf(__expf(2.0f * x) + 1.0f);
}
__device__ __forceinline__ float combine(const float acc[4], float& c) {
  float ig = sigf(acc[0]);
  float fg = sigf(acc[1]);
  float gg = tanh_f(acc[2]);
  float og = sigf(acc[3]);
  c = fg * c + ig * gg;
  return og * tanh_f(c);
}

// packed f16 dual-MAC: acc += w.lo*h.lo + w.hi*h.hi
__device__ __forceinline__ float dot2f(u32 w, u32 h, float acc) {
#if __has_builtin(__builtin_amdgcn_fdot2)
  return __builtin_amdgcn_fdot2(__builtin_bit_cast(half2v, w),
                                __builtin_bit_cast(half2v, h), acc, false);
#else
  half2v a = __builtin_bit_cast(half2v, w), b = __builtin_bit_cast(half2v, h);
  acc = fmaf((float)a.x, (float)b.x, acc);
  return fmaf((float)a.y, (float)b.y, acc);
#endif
}

__device__ __forceinline__ void ld4(uint4* dst, const u32* src) {
#pragma unroll
  for (int i = 0; i < 4; ++i) dst[i] = ((const uint4*)src)[i];
}

// 4-gate dot over K=8*NPH elems; W rows at jbase + g*32*RS, f16x2 packed
template<int NPH, int RS>
__device__ __forceinline__ void celldot(const u32* W, int jbase, const uint4* hv, float acc[4]) {
#pragma unroll
  for (int p = 0; p < NPH; ++p) {
    uint4 hq = hv[p];
#pragma unroll
    for (int g = 0; g < 4; ++g) {
      uint4 w = *(const uint4*)(W + jbase + g * 32 * RS + 4 * p);
      acc[g] = dot2f(w.x, hq.x, acc[g]);
      acc[g] = dot2f(w.y, hq.y, acc[g]);
      acc[g] = dot2f(w.z, hq.z, acc[g]);
      acc[g] = dot2f(w.w, hq.w, acc[g]);
    }
  }
}

__global__ __launch_bounds__(NT, 1) void lstm_kernel(
    const void* __restrict__ xg,
    const void* Wih_f0, const void* Whh_f0, const void* b_f0,
    const void* Wih_f1, const void* Whh_f1, const void* b_f1,
    const void* Wih_b0, const void* Whh_b0, const void* b_b0,
    const void* Wih_b1, const void* Whh_b1, const void* b_b1,
    const void* Wlin, const void* blin, const int* __restrict__ futp,
    void* __restrict__ outp) {
  __shared__ SMem sm;
  const int tid = threadIdx.x;
  const int bid = blockIdx.x;
  const int wv = tid >> 6;          // wave 0..3
  const int lane = tid & 63;
  const int b2 = lane >> 5;         // batch-in-wave 0..1
  const int j = lane & 31;          // h index 0..31
  const int gb = bid * 8 + wv * 2 + b2;  // global batch

  // ---- dtype detection (uniform): bf16-pairs read as fp32 are implausible ----
  bool bfm;
  {
    const float* xf = (const float*)xg;
    int bad = 0;
    for (int i = 0; i < 64; ++i) {
      float a = fabsf(xf[i]);
      bool ok = (a == 0.0f) || (a > 1e-8f && a < 1e4f);
      if (!ok) bad = 1;
    }
    bfm = (bad != 0);
  }

  // ---- stage weights into LDS as packed f16x2 (bf16->f16 is exact) ----
  for (int idx = tid; idx < 128 * 32; idx += NT) {
    int r = idx >> 5, d = idx & 31;
    int src = (d < 16) ? (r * 32 + 2 * d) : (r * 32 + 2 * (d - 16));
    const void* pf = (d < 16) ? Wih_f1 : Whh_f1;
    const void* pb = (d < 16) ? Wih_b1 : Whh_b1;
    sm.Wf1[r * WS1 + d] = pack2h(ldin(pf, src, bfm), ldin(pf, src + 1, bfm));
    sm.Wb1[r * WS1 + d] = pack2h(ldin(pb, src, bfm), ldin(pb, src + 1, bfm));
  }
  for (int idx = tid; idx < 128 * 16; idx += NT) {
    int r = idx >> 4, d = idx & 15;
    int src = r * 32 + 2 * d;
    sm.W0f[r * WS0 + d] = pack2h(ldin(Whh_f0, src, bfm), ldin(Whh_f0, src + 1, bfm));
    sm.W0b[r * WS0 + d] = pack2h(ldin(Whh_b0, src, bfm), ldin(Whh_b0, src + 1, bfm));
  }
  for (int idx = tid; idx < 3 * 4 * 2 * 20; idx += NT) (&sm.h[0][0][0][0])[idx] = 0u;
  __syncthreads();  // only barrier: weights ready, h zeroed

  // ---- per-lane register-cached constants ----
  float bf0[4], bb0[4], bf1[4], bb1[4], wxf[4], wxb[4];
#pragma unroll
  for (int g = 0; g < 4; ++g) {
    int r = g * 32 + j;
    bf0[g] = ldin(b_f0, r, bfm);
    bf1[g] = ldin(b_f1, r, bfm);
    bb0[g] = ldin(b_b0, r, bfm);
    bb1[g] = ldin(b_b1, r, bfm);
    wxf[g] = ldin(Wih_f0, r, bfm);
    wxb[g] = ldin(Wih_b0, r, bfm);
  }
  const float wlj0 = ldin(Wlin, j, bfm);
  const float wlj1 = ldin(Wlin, 32 + j, bfm);
  const float blv = ldin(blin, 0, bfm);
  const int fut = *futp;

  u32* const hF0 = &sm.h[0][wv][b2][0];
  u32* const hB0 = &sm.h[1][wv][b2][0];
  u32* const hF1 = &sm.h[2][wv][b2][0];
  const int jb1 = j * WS1, jb0 = j * WS0;

  // ---- time loop: no __syncthreads; each wave fully owns its 2 batches ----
  float c_f0 = 0.f, c_f1 = 0.f, c_b0 = 0.f, c_b1 = 0.f;
  float xf_c = ldin(xg, 0 * BB + gb, bfm);
  float xb_c = ldin(xg, (((fut % SS) + SS) % SS) * BB + gb, bfm);

  for (int t = 0; t < SS; ++t) {
    // prefetch next step's x (consumed at loop end; vmcnt hidden under compute)
    float xf_n = 0.f, xb_n = 0.f;
    if (t + 1 < SS) {
      xf_n = ldin(xg, (t + 1) * BB + gb, bfm);
      int ib = (((fut - (t + 1)) % SS) + SS) % SS;
      xb_n = ldin(xg, ib * BB + gb, bfm);
    }

    // --- f0 / b0 (read h_{t-1}) ---
    float hnf0, hnb0;
    {
      uint4 hv[4];
      ld4(hv, hF0);
      float a[4];
#pragma unroll
      for (int g = 0; g < 4; ++g) a[g] = fmaf(wxf[g], xf_c, bf0[g]);
      celldot<4, WS0>(sm.W0f, jb0, hv, a);
      hnf0 = combine(a, c_f0);
    }
    {
      uint4 hv[4];
      ld4(hv, hB0);
      float a[4];
#pragma unroll
      for (int g = 0; g < 4; ++g) a[g] = fmaf(wxb[g], xb_c, bb0[g]);
      celldot<4, WS0>(sm.W0b, jb0, hv, a);
      hnb0 = combine(a, c_b0);
    }
    // publish hf0,hb0 (same-wave DS ops are in-order; fence blocks compiler reorder)
    ((_Float16*)hF0)[j] = (_Float16)hnf0;
    ((_Float16*)hB0)[j] = (_Float16)hnb0;
    LDS_FENCE();

    // --- f1: inp = new hf0, rec = old hf1 ---
    float hnf1;
    {
      uint4 hv[8];
      ld4(hv, hF0);
      ld4(hv + 4, hF1);
      float a[4] = {bf1[0], bf1[1], bf1[2], bf1[3]};
      celldot<8, WS1>(sm.Wf1, jb1, hv, a);
      hnf1 = combine(a, c_f1);
    }
    ((_Float16*)hF1)[j] = (_Float16)hnf1;
    LDS_FENCE();

    // --- b1 (reference bug): inp = new hb0, rec = NEW hf1, c = c_b1 ---
    float hnb1;
    {
      uint4 hv[8];
      ld4(hv, hB0);
      ld4(hv + 4, hF1);
      float a[4] = {bb1[0], bb1[1], bb1[2], bb1[3]};
      celldot<8, WS1>(sm.Wb1, jb1, hv, a);
      hnb1 = combine(a, c_b1);
    }

    // --- output head: in-register shuffle reduction over j (hb1 never hits LDS) ---
    float contrib = fmaf(wlj0, hnf1, wlj1 * hnb1);
#pragma unroll
    for (int m = 1; m <= 16; m <<= 1) contrib += __shfl_xor(contrib, m, 64);
    if (j == 0) {
      float o = contrib + blv;
      size_t pos = (size_t)gb * SS + (size_t)t;
      if (bfm) ((u16*)outp)[pos] = f2bf(o);
      else     ((float*)outp)[pos] = o;
    }

    xf_c = xf_n;
    xb_c = xb_n;
  }
}

extern "C" void kernel_launch(void* const* d_in, const int* in_sizes, int n_in,
                              void* d_out, int out_size, void* d_ws, size_t ws_size,
                              hipStream_t stream) {
  (void)in_sizes; (void)n_in; (void)out_size; (void)d_ws; (void)ws_size;
  lstm_kernel<<<dim3(BB / 8), dim3(NT), 0, stream>>>(
      d_in[0], d_in[1], d_in[2], d_in[3], d_in[4], d_in[5], d_in[6],
      d_in[7], d_in[8], d_in[9], d_in[10], d_in[11], d_in[12],
      d_in[13], d_in[14], (const int*)d_in[15], d_out);
}

// Round 3
// 1650.114 us; speedup vs baseline: 3.4078x; 1.4485x over previous
//
#include <hip/hip_runtime.h>

#define SS 1024
#define BB 2048
#define NT 256
#define GRID 512   // 4 waves/block, 1 batch/wave -> 512*4 = 2048 batches

typedef unsigned int u32;
typedef unsigned short u16;
typedef _Float16 half2v __attribute__((ext_vector_type(2)));

#define LDS_FENCE() asm volatile("s_waitcnt lgkmcnt(0)" ::: "memory")

// ---------- helpers ----------
__device__ __forceinline__ u16 f2bf(float f) {  // RNE fp32->bf16
  u32 u = __float_as_uint(f);
  return (u16)((u + 0x7fffu + ((u >> 16) & 1u)) >> 16);
}
__device__ __forceinline__ float ldin(const void* p, int i, bool bf) {
  if (bf) { u16 v = ((const u16*)p)[i]; return __uint_as_float(((u32)v) << 16); }
  return ((const float*)p)[i];
}
__device__ __forceinline__ u32 pack2h(float a, float b) {  // two f32 -> packed f16x2 (RNE)
  _Float16 ha = (_Float16)a, hb = (_Float16)b;
  u16 ua = __builtin_bit_cast(u16, ha), ub = __builtin_bit_cast(u16, hb);
  return (u32)ua | ((u32)ub << 16);
}
__device__ __forceinline__ float sigf(float x) {
  return __builtin_amdgcn_rcpf(1.0f + __expf(-x));
}
__device__ __forceinline__ float tanh_f(float x) {
  return 1.0f - 2.0f * __builtin_amdgcn_rcpf(__expf(2.0f * x) + 1.0f);
}
__device__ __forceinline__ float combine(const float acc[4], float& c) {
  float ig = sigf(acc[0]);
  float fg = sigf(acc[1]);
  float gg = tanh_f(acc[2]);
  float og = sigf(acc[3]);
  c = fg * c + ig * gg;
  return og * tanh_f(c);
}
// packed f16 dual-MAC into f32: acc += w.lo*h.lo + w.hi*h.hi
__device__ __forceinline__ float dot2f(u32 w, u32 h, float acc) {
#if __has_builtin(__builtin_amdgcn_fdot2)
  return __builtin_amdgcn_fdot2(__builtin_bit_cast(half2v, w),
                                __builtin_bit_cast(half2v, h), acc, false);
#else
  half2v a = __builtin_bit_cast(half2v, w), b = __builtin_bit_cast(half2v, h);
  acc = fmaf((float)a.x, (float)b.x, acc);
  return fmaf((float)a.y, (float)b.y, acc);
#endif
}

__global__ __launch_bounds__(NT, 2) void lstm_kernel(
    const void* __restrict__ xg,
    const void* Wih_f0, const void* Whh_f0, const void* b_f0,
    const void* Wih_f1, const void* Whh_f1, const void* b_f1,
    const void* Wih_b0, const void* Whh_b0, const void* b_b0,
    const void* Wih_b1, const void* Whh_b1, const void* b_b1,
    const void* Wlin, const void* blin, const int* __restrict__ futp,
    void* __restrict__ outp) {
  // h-exchange only; weights live in registers. 768 B of LDS total.
  __shared__ __align__(16) _Float16 h0[4][2][32];  // [wave][dir][j] layer-0 h
  __shared__ __align__(16) _Float16 h1[4][32];     // [wave][j]       hf1

  const int tid = threadIdx.x, bid = blockIdx.x;
  const int wv = tid >> 6, lane = tid & 63;
  const int j = lane & 31, dir = lane >> 5;   // dir 0 = forward cells, 1 = backward cells
  const int gb = bid * 4 + wv;                // global batch (1 per wave)

  // ---- dtype detection (uniform): bf16-pairs read as fp32 are implausible ----
  bool bfm;
  {
    const float* xf = (const float*)xg;
    int bad = 0;
    for (int i = 0; i < 64; ++i) {
      float a = fabsf(xf[i]);
      bool ok = (a == 0.0f) || (a > 1e-8f && a < 1e4f);
      if (!ok) bad = 1;
    }
    bfm = (bad != 0);
  }

  // ---- per-lane weight residency: 192 VGPRs of packed f16x2 ----
  const void* s0  = dir ? Whh_b0 : Whh_f0;   // layer-0 recurrent 128x32
  const void* sA  = dir ? Wih_b1 : Wih_f1;   // layer-1 input     128x32
  const void* sB  = dir ? Whh_b1 : Whh_f1;   // layer-1 recurrent 128x32
  const void* pb0 = dir ? b_b0 : b_f0;
  const void* pb1 = dir ? b_b1 : b_f1;
  const void* pwx = dir ? Wih_b0 : Wih_f0;   // layer-0 input col 128x1

  u32 w0[64];    // 4 gates x 16 dw (K=32)
  u32 w1[128];   // 4 gates x 32 dw (K=64: [inp|rec])
#pragma unroll
  for (int g = 0; g < 4; ++g) {
    int r = (g * 32 + j) * 32;
#pragma unroll
    for (int d = 0; d < 16; ++d)
      w0[g * 16 + d] = pack2h(ldin(s0, r + 2 * d, bfm), ldin(s0, r + 2 * d + 1, bfm));
#pragma unroll
    for (int d = 0; d < 16; ++d)
      w1[g * 32 + d] = pack2h(ldin(sA, r + 2 * d, bfm), ldin(sA, r + 2 * d + 1, bfm));
#pragma unroll
    for (int d = 0; d < 16; ++d)
      w1[g * 32 + 16 + d] = pack2h(ldin(sB, r + 2 * d, bfm), ldin(sB, r + 2 * d + 1, bfm));
  }
  float b0v[4], b1v[4], wxv[4];
#pragma unroll
  for (int g = 0; g < 4; ++g) {
    b0v[g] = ldin(pb0, g * 32 + j, bfm);
    b1v[g] = ldin(pb1, g * 32 + j, bfm);
    wxv[g] = ldin(pwx, g * 32 + j, bfm);
  }
  const float wl = ldin(Wlin, dir * 32 + j, bfm);
  const float blv = ldin(blin, 0, bfm);
  const int fut = *futp;

  _Float16* const my0 = &h0[wv][dir][0];   // own layer-0 h row (also layer-1 input row)
  _Float16* const myh1 = &h1[wv][0];       // shared hf1 row

  // zero-init h state
  my0[j] = (_Float16)0.f;
  if (!dir) myh1[j] = (_Float16)0.f;
  LDS_FENCE();

  // fwd lanes: step t=u. bwd lanes run one step skewed: t' = u-1.
  float c0 = 0.f, c1 = 0.f, h1prev = 0.f;
  float x_cur = ldin(xg, (dir ? ((fut + 1) & (SS - 1)) : 0) * BB + gb, bfm);

  for (int u = 0; u <= SS; ++u) {
    // prefetch next x: fwd -> x[u+1] (clamped), bwd -> xb[t'=u] = x[(fut-u) mod S]
    int idxn = dir ? ((fut - u) & (SS - 1)) : ((u + 1 < SS) ? (u + 1) : (SS - 1));
    float x_n = ldin(xg, idxn * BB + gb, bfm);

    // ---- layer 0 (fwd: f0 @ t=u ; bwd: b0 @ t'=u-1) ----
    uint4 hv0[4];
#pragma unroll
    for (int i = 0; i < 4; ++i) hv0[i] = ((const uint4*)my0)[i];
    const u32* hd0 = (const u32*)hv0;
    float acc[4];
#pragma unroll
    for (int g = 0; g < 4; ++g) acc[g] = fmaf(wxv[g], x_cur, b0v[g]);
#pragma unroll
    for (int g = 0; g < 4; ++g)
#pragma unroll
      for (int d = 0; d < 16; ++d) acc[g] = dot2f(w0[g * 16 + d], hd0[d], acc[g]);
    float hn0 = combine(acc, c0);
    const bool kill = (u == 0) && dir;   // bwd lanes at u=0 computed garbage (t'=-1)
    if (kill) { hn0 = 0.f; c0 = 0.f; }
    my0[j] = (_Float16)hn0;
    LDS_FENCE();

    // ---- layer 1 (fwd: f1 @ t=u, rec=hf1(u-1) ; bwd: b1 @ t'=u-1, rec=hf1(u-1)=NEW hf1 at t' per ref bug) ----
    uint4 hv1[8];
#pragma unroll
    for (int i = 0; i < 4; ++i) hv1[i] = ((const uint4*)my0)[i];        // inp: own new layer-0 h
#pragma unroll
    for (int i = 0; i < 4; ++i) hv1[4 + i] = ((const uint4*)myh1)[i];   // rec: hf1 (pre-update)
    const u32* hd1 = (const u32*)hv1;
#pragma unroll
    for (int g = 0; g < 4; ++g) acc[g] = b1v[g];
#pragma unroll
    for (int g = 0; g < 4; ++g)
#pragma unroll
      for (int d = 0; d < 32; ++d) acc[g] = dot2f(w1[g * 32 + d], hd1[d], acc[g]);
    float hn1 = combine(acc, c1);
    if (kill) c1 = 0.f;

    // ---- output head for t' = u-1: sum_j wlin[j]*hf1(t')[j] + wlin[32+j]*hb1(t')[j] ----
    float myh = dir ? hn1 : h1prev;      // fwd contributes previous-step hf1
    float contrib = wl * myh;
#pragma unroll
    for (int m = 1; m <= 32; m <<= 1) contrib += __shfl_xor(contrib, m, 64);
    if (u > 0) {                          // uniform guard
      if (lane == 0) {
        float o = contrib + blv;
        size_t pos = (size_t)gb * SS + (size_t)(u - 1);
        if (bfm) ((u16*)outp)[pos] = f2bf(o);
        else     ((float*)outp)[pos] = o;
      }
    }
    h1prev = hn1;

    // publish hf1(u) for next iteration's bwd read (skip at u==SS: bwd still needs hf1(SS-1))
    if (u < SS) {
      if (!dir) myh1[j] = (_Float16)hn1;
    }
    LDS_FENCE();
    x_cur = x_n;
  }
}

extern "C" void kernel_launch(void* const* d_in, const int* in_sizes, int n_in,
                              void* d_out, int out_size, void* d_ws, size_t ws_size,
                              hipStream_t stream) {
  (void)in_sizes; (void)n_in; (void)out_size; (void)d_ws; (void)ws_size;
  lstm_kernel<<<dim3(GRID), dim3(NT), 0, stream>>>(
      d_in[0], d_in[1], d_in[2], d_in[3], d_in[4], d_in[5], d_in[6],
      d_in[7], d_in[8], d_in[9], d_in[10], d_in[11], d_in[12],
      d_in[13], d_in[14], (const int*)d_in[15], d_out);
}

// Round 5
// 1518.383 us; speedup vs baseline: 3.7034x; 1.0868x over previous
//
#include <hip/hip_runtime.h>

#define SS 1024
#define BB 2048
#define NT 256
#define GRID 512   // 4 waves/block, 1 batch/wave -> 2048 batches

typedef unsigned int u32;
typedef unsigned short u16;
typedef _Float16 half2v __attribute__((ext_vector_type(2)));
typedef __fp16 fp16x2 __attribute__((ext_vector_type(2)));

#define LDS_FENCE() asm volatile("s_waitcnt lgkmcnt(0)" ::: "memory")

// ---------- helpers ----------
__device__ __forceinline__ u16 f2bf(float f) {  // RNE fp32->bf16
  u32 u = __float_as_uint(f);
  return (u16)((u + 0x7fffu + ((u >> 16) & 1u)) >> 16);
}
template<bool BFM>
__device__ __forceinline__ float ldin(const void* p, int i) {
  if (BFM) { u16 v = ((const u16*)p)[i]; return __uint_as_float(((u32)v) << 16); }
  return ((const float*)p)[i];
}
__device__ __forceinline__ u32 packrtz(float lo, float hi) {
#if __has_builtin(__builtin_amdgcn_cvt_pkrtz)
  fp16x2 h = __builtin_amdgcn_cvt_pkrtz(lo, hi);
  return __builtin_bit_cast(u32, h);
#else
  _Float16 ha = (_Float16)lo, hb = (_Float16)hi;
  return (u32)__builtin_bit_cast(u16, ha) | ((u32)__builtin_bit_cast(u16, hb) << 16);
#endif
}
// load weight elems {i, i+1} (i even) -> packed f16x2 (bf16->f16 exact for these ranges)
template<bool BFM>
__device__ __forceinline__ u32 ldpack(const void* p, int i) {
  if (BFM) {
    u32 pr = *(const u32*)((const u16*)p + i);           // two bf16 in one dword
    return packrtz(__uint_as_float(pr << 16), __uint_as_float(pr & 0xffff0000u));
  }
  return packrtz(((const float*)p)[i], ((const float*)p)[i + 1]);
}
__device__ __forceinline__ float sigf(float x) {
  return __builtin_amdgcn_rcpf(1.0f + __expf(-x));
}
__device__ __forceinline__ float tanh_f(float x) {
  return 1.0f - 2.0f * __builtin_amdgcn_rcpf(__expf(2.0f * x) + 1.0f);
}
__device__ __forceinline__ float combine(const float acc[4], float& c) {
  float ig = sigf(acc[0]);
  float fg = sigf(acc[1]);
  float gg = tanh_f(acc[2]);
  float og = sigf(acc[3]);
  c = fg * c + ig * gg;
  return og * tanh_f(c);
}
// packed f16 dual-MAC into f32
__device__ __forceinline__ float dot2f(u32 w, u32 h, float acc) {
#if __has_builtin(__builtin_amdgcn_fdot2)
  return __builtin_amdgcn_fdot2(__builtin_bit_cast(half2v, w),
                                __builtin_bit_cast(half2v, h), acc, false);
#else
  half2v a = __builtin_bit_cast(half2v, w), b = __builtin_bit_cast(half2v, h);
  acc = fmaf((float)a.x, (float)b.x, acc);
  return fmaf((float)a.y, (float)b.y, acc);
#endif
}

template<bool BFM>
__device__ __forceinline__ void run(
    const void* xg,
    const void* Wih_f0, const void* Whh_f0, const void* b_f0,
    const void* Wih_f1, const void* Whh_f1, const void* b_f1,
    const void* Wih_b0, const void* Whh_b0, const void* b_b0,
    const void* Wih_b1, const void* Whh_b1, const void* b_b1,
    const void* Wlin, const void* blin, const int* futp, void* outp,
    _Float16 (*h0)[2][32], _Float16 (*h1)[32], int tid, int bid) {
  const int wv = tid >> 6, lane = tid & 63;
  const int j = lane & 31, dir = lane >> 5;   // dir 0: f0/f1 cells, dir 1: b0/b1 cells
  const int gb = bid * 4 + wv;                // 1 batch per wave

  const void* s0  = dir ? Whh_b0 : Whh_f0;
  const void* sA  = dir ? Wih_b1 : Wih_f1;
  const void* sB  = dir ? Whh_b1 : Whh_f1;
  const void* pb0 = dir ? b_b0 : b_f0;
  const void* pb1 = dir ? b_b1 : b_f1;
  const void* pwx = dir ? Wih_b0 : Wih_f0;

  // ---- per-lane weight residency: 192 dw packed f16x2, straight-line staging ----
  u32 w0[64];    // layer-0 rec: 4 gates x 16 dw (K=32)
  u32 w1[128];   // layer-1:     4 gates x (16 inp + 16 rec) dw (K=64)
#pragma unroll
  for (int g = 0; g < 4; ++g) {
    const int r = (g * 32 + j) * 32;
#pragma unroll
    for (int d = 0; d < 16; ++d) w0[g * 16 + d] = ldpack<BFM>(s0, r + 2 * d);
#pragma unroll
    for (int d = 0; d < 16; ++d) w1[g * 32 + d] = ldpack<BFM>(sA, r + 2 * d);
#pragma unroll
    for (int d = 0; d < 16; ++d) w1[g * 32 + 16 + d] = ldpack<BFM>(sB, r + 2 * d);
  }
  float b0v[4], b1v[4], wxv[4];
#pragma unroll
  for (int g = 0; g < 4; ++g) {
    b0v[g] = ldin<BFM>(pb0, g * 32 + j);
    b1v[g] = ldin<BFM>(pb1, g * 32 + j);
    wxv[g] = ldin<BFM>(pwx, g * 32 + j);
  }
  const float wl  = ldin<BFM>(Wlin, dir * 32 + j);
  const float blv = ldin<BFM>(blin, 0);
  const int fut = *futp;

  _Float16* const my0  = &h0[wv][dir][0];
  _Float16* const myh1 = &h1[wv][0];
  my0[j] = (_Float16)0.f;
  if (!dir) myh1[j] = (_Float16)0.f;
  LDS_FENCE();

  // fwd lanes compute step t=u; bwd lanes run one step skewed (t' = u-1).
  float c0 = 0.f, c1 = 0.f, h1prev = 0.f;
  float x_cur = ldin<BFM>(xg, (dir ? ((fut + 1) & (SS - 1)) : 0) * BB + gb);

  for (int u = 0; u <= SS; ++u) {
    int idxn = dir ? ((fut - u) & (SS - 1)) : ((u + 1 < SS) ? (u + 1) : (SS - 1));
    float x_n = ldin<BFM>(xg, idxn * BB + gb);

    // ---- layer 0 (fwd: f0@u ; bwd: b0@u-1); q-outer keeps only 4 h-dw live ----
    float acc[4];
#pragma unroll
    for (int g = 0; g < 4; ++g) acc[g] = fmaf(wxv[g], x_cur, b0v[g]);
    {
      const uint4* hp = (const uint4*)my0;
#pragma unroll
      for (int q = 0; q < 4; ++q) {
        uint4 hq = hp[q];
#pragma unroll
        for (int g = 0; g < 4; ++g) {
          acc[g] = dot2f(w0[g * 16 + 4 * q + 0], hq.x, acc[g]);
          acc[g] = dot2f(w0[g * 16 + 4 * q + 1], hq.y, acc[g]);
          acc[g] = dot2f(w0[g * 16 + 4 * q + 2], hq.z, acc[g]);
          acc[g] = dot2f(w0[g * 16 + 4 * q + 3], hq.w, acc[g]);
        }
      }
    }
    float hn0 = combine(acc, c0);
    if ((u == 0) && dir) { hn0 = 0.f; c0 = 0.f; }   // bwd u=0 computed t'=-1 garbage
    my0[j] = (_Float16)hn0;
    LDS_FENCE();

    // ---- layer 1 (fwd: f1@u rec=hf1(u-1) ; bwd: b1@u-1 rec=NEW hf1(u-1) per ref bug) ----
#pragma unroll
    for (int g = 0; g < 4; ++g) acc[g] = b1v[g];
    {
      const uint4* hp = (const uint4*)my0;            // inp: own new layer-0 h
#pragma unroll
      for (int q = 0; q < 4; ++q) {
        uint4 hq = hp[q];
#pragma unroll
        for (int g = 0; g < 4; ++g) {
          acc[g] = dot2f(w1[g * 32 + 4 * q + 0], hq.x, acc[g]);
          acc[g] = dot2f(w1[g * 32 + 4 * q + 1], hq.y, acc[g]);
          acc[g] = dot2f(w1[g * 32 + 4 * q + 2], hq.z, acc[g]);
          acc[g] = dot2f(w1[g * 32 + 4 * q + 3], hq.w, acc[g]);
        }
      }
      const uint4* hr = (const uint4*)myh1;           // rec: hf1 (pre-update)
#pragma unroll
      for (int q = 0; q < 4; ++q) {
        uint4 hq = hr[q];
#pragma unroll
        for (int g = 0; g < 4; ++g) {
          acc[g] = dot2f(w1[g * 32 + 16 + 4 * q + 0], hq.x, acc[g]);
          acc[g] = dot2f(w1[g * 32 + 16 + 4 * q + 1], hq.y, acc[g]);
          acc[g] = dot2f(w1[g * 32 + 16 + 4 * q + 2], hq.z, acc[g]);
          acc[g] = dot2f(w1[g * 32 + 16 + 4 * q + 3], hq.w, acc[g]);
        }
      }
    }
    float hn1 = combine(acc, c1);
    if ((u == 0) && dir) c1 = 0.f;

    // ---- output head for t'=u-1 ----
    float myh = dir ? hn1 : h1prev;
    float contrib = wl * myh;
#pragma unroll
    for (int m = 1; m <= 32; m <<= 1) contrib += __shfl_xor(contrib, m, 64);
    if (u > 0 && lane == 0) {
      float o = contrib + blv;
      size_t pos = (size_t)gb * SS + (size_t)(u - 1);
      if (BFM) ((u16*)outp)[pos] = f2bf(o);
      else     ((float*)outp)[pos] = o;
    }
    h1prev = hn1;

    if (u < SS && !dir) myh1[j] = (_Float16)hn1;  // publish hf1(u) for next iter's bwd
    LDS_FENCE();
    x_cur = x_n;
  }
}

__global__ __launch_bounds__(NT, 2) void lstm_kernel(
    const void* __restrict__ xg,
    const void* Wih_f0, const void* Whh_f0, const void* b_f0,
    const void* Wih_f1, const void* Whh_f1, const void* b_f1,
    const void* Wih_b0, const void* Whh_b0, const void* b_b0,
    const void* Wih_b1, const void* Whh_b1, const void* b_b1,
    const void* Wlin, const void* blin, const int* __restrict__ futp,
    void* __restrict__ outp) {
  __shared__ __align__(16) _Float16 h0s[4][2][32];
  __shared__ __align__(16) _Float16 h1s[4][32];

  // dtype detection (uniform): bf16-pairs read as fp32 are implausible as N(0,1)
  bool bfm;
  {
    const float* xf = (const float*)xg;
    int bad = 0;
    for (int i = 0; i < 64; ++i) {
      float a = fabsf(xf[i]);
      bool ok = (a == 0.0f) || (a > 1e-8f && a < 1e4f);
      if (!ok) bad = 1;
    }
    bfm = (bad != 0);
  }

  if (bfm)
    run<true>(xg, Wih_f0, Whh_f0, b_f0, Wih_f1, Whh_f1, b_f1,
              Wih_b0, Whh_b0, b_b0, Wih_b1, Whh_b1, b_b1,
              Wlin, blin, futp, outp, h0s, h1s, threadIdx.x, blockIdx.x);
  else
    run<false>(xg, Wih_f0, Whh_f0, b_f0, Wih_f1, Whh_f1, b_f1,
               Wih_b0, Whh_b0, b_b0, Wih_b1, Whh_b1, b_b1,
               Wlin, blin, futp, outp, h0s, h1s, threadIdx.x, blockIdx.x);
}

extern "C" void kernel_launch(void* const* d_in, const int* in_sizes, int n_in,
                              void* d_out, int out_size, void* d_ws, size_t ws_size,
                              hipStream_t stream) {
  (void)in_sizes; (void)n_in; (void)out_size; (void)d_ws; (void)ws_size;
  lstm_kernel<<<dim3(GRID), dim3(NT), 0, stream>>>(
      d_in[0], d_in[1], d_in[2], d_in[3], d_in[4], d_in[5], d_in[6],
      d_in[7], d_in[8], d_in[9], d_in[10], d_in[11], d_in[12],
      d_in[13], d_in[14], (const int*)d_in[15], d_out);
}